// Round 1
// baseline (435.149 us; speedup 1.0000x reference)
//
#include <hip/hip_runtime.h>

// ---------------------------------------------------------------------------
// CausalCrossAttention (GroupNorm -> q proj -> block-causal cross-attn -> o proj + residual)
// B=2 C=512 T=16 H=W=32 (P = T*HW = 16384 per batch), S=64 D=1024, groups=32.
// Heavy GEMMs use f16 hi/lo split (3-term MFMA) for f32-grade accuracy.
// ---------------------------------------------------------------------------

typedef float    f32x4 __attribute__((ext_vector_type(4)));
typedef _Float16 half8 __attribute__((ext_vector_type(8)));
typedef _Float16 half4 __attribute__((ext_vector_type(4)));

#define GLB_AS __attribute__((address_space(1)))
#define LDS_AS __attribute__((address_space(3)))

__device__ __forceinline__ void gload_lds16(const void* g, void* l) {
  __builtin_amdgcn_global_load_lds((const GLB_AS void*)g, (LDS_AS void*)l, 16, 0, 0);
}

// ---------------------------------------------------------------------------
// 1) GroupNorm statistics: one block per (b, g, t); 16 ch * 1024 hw = 16384 elems
// ---------------------------------------------------------------------------
__global__ __launch_bounds__(256) void gn_stats(const float* __restrict__ x,
                                                float* __restrict__ muA,
                                                float* __restrict__ rsA)
{
  const int t = blockIdx.x, g = blockIdx.y, b = blockIdx.z;
  const int tid = threadIdx.x;
  float s1 = 0.f, s2 = 0.f;
#pragma unroll
  for (int c = 0; c < 16; ++c) {
    const long base = (((long)(b * 512 + g * 16 + c) * 16 + t) << 10) + tid * 4;
    const f32x4 v = *(const f32x4*)&x[base];
    s1 += v[0] + v[1] + v[2] + v[3];
    s2 += v[0] * v[0] + v[1] * v[1] + v[2] * v[2] + v[3] * v[3];
  }
  for (int o = 32; o; o >>= 1) { s1 += __shfl_down(s1, o); s2 += __shfl_down(s2, o); }
  __shared__ float r1[4], r2[4];
  const int w = tid >> 6;
  if ((tid & 63) == 0) { r1[w] = s1; r2[w] = s2; }
  __syncthreads();
  if (tid == 0) {
    const float a = r1[0] + r1[1] + r1[2] + r1[3];
    const float q = r2[0] + r2[1] + r2[2] + r2[3];
    const float mu = a * (1.f / 16384.f);
    const float var = q * (1.f / 16384.f) - mu * mu;
    const int idx = (b * 32 + g) * 16 + t;
    muA[idx] = mu;
    rsA[idx] = 1.f / sqrtf(var + 1e-5f);
  }
}

// ---------------------------------------------------------------------------
// 2) Apply GN + transpose x[b][c][p] -> h[b][p][c], split into f16 hi/lo
// ---------------------------------------------------------------------------
__global__ __launch_bounds__(256) void gn_apply(const float* __restrict__ x,
                                                const float* __restrict__ muA,
                                                const float* __restrict__ rsA,
                                                const float* __restrict__ gamma,
                                                const float* __restrict__ beta,
                                                _Float16* __restrict__ hHi,
                                                _Float16* __restrict__ hLo)
{
  const int b = blockIdx.z;
  const int c0 = blockIdx.y * 64;
  const int p0 = blockIdx.x * 64;
  const int t = p0 >> 10;                 // 64-wide p tile never crosses a frame
  __shared__ float tile[64 * 65];
  const int tid = threadIdx.x;
  const int rr = tid >> 4;                // 0..15
  const int col4 = (tid & 15) * 4;
#pragma unroll
  for (int i = 0; i < 4; ++i) {
    const int r = i * 16 + rr;
    const int c = c0 + r;
    const int gi = (b * 32 + (c >> 4)) * 16 + t;
    const float s = rsA[gi] * gamma[c];
    const float o = beta[c] - muA[gi] * s;
    const f32x4 v = *(const f32x4*)&x[(((long)b * 512 + c) << 14) + p0 + col4];
    tile[r * 65 + col4 + 0] = v[0] * s + o;
    tile[r * 65 + col4 + 1] = v[1] * s + o;
    tile[r * 65 + col4 + 2] = v[2] * s + o;
    tile[r * 65 + col4 + 3] = v[3] * s + o;
  }
  __syncthreads();
  const int pr = tid >> 2;                // 0..63
  const int cs = (tid & 3) * 16;
  const long obase = (((long)b * 16384 + p0 + pr) << 9) + c0 + cs;
  half8 h0, h1, l0, l1;
#pragma unroll
  for (int j = 0; j < 16; ++j) {
    const float vv = tile[(cs + j) * 65 + pr];
    const _Float16 hi = (_Float16)vv;
    const _Float16 lo = (_Float16)(vv - (float)hi);
    if (j < 8) { h0[j] = hi; l0[j] = lo; } else { h1[j - 8] = hi; l1[j - 8] = lo; }
  }
  *(half8*)&hHi[obase]     = h0;
  *(half8*)&hHi[obase + 8] = h1;
  *(half8*)&hLo[obase]     = l0;
  *(half8*)&hLo[obase + 8] = l1;
}

// ---------------------------------------------------------------------------
// 3) f32 -> f16 hi/lo split for weight matrices (layout preserved)
// ---------------------------------------------------------------------------
__global__ void split_w(const float* __restrict__ src, _Float16* __restrict__ hi,
                        _Float16* __restrict__ lo, int n4)
{
  const int i = blockIdx.x * blockDim.x + threadIdx.x;
  if (i >= n4) return;
  const f32x4 v = *(const f32x4*)&src[i * 4];
  half4 h, l;
#pragma unroll
  for (int j = 0; j < 4; ++j) {
    const _Float16 hh = (_Float16)v[j];
    h[j] = hh;
    l[j] = (_Float16)(v[j] - (float)hh);
  }
  *(half4*)&hi[i * 4] = h;
  *(half4*)&lo[i * 4] = l;
}

// ---------------------------------------------------------------------------
// 4) kv projection: kv[b,s,o] = ctx[b,s,:] . wkv[o,:] + bkv[o]
//    k written transposed kT[b][c][s]; v written v[b][s][c]. Wave-per-dot.
// ---------------------------------------------------------------------------
__global__ __launch_bounds__(256) void kv_proj(const float* __restrict__ ctx,
                                               const float* __restrict__ wkv,
                                               const float* __restrict__ bkv,
                                               float* __restrict__ kT,
                                               float* __restrict__ vOut)
{
  const int b = blockIdx.z;
  const int s0 = blockIdx.y * 16;
  const int o0 = blockIdx.x * 16;
  const int tid = threadIdx.x, lane = tid & 63, w = tid >> 6;
  for (int it = 0; it < 64; ++it) {
    const int idx = w * 64 + it;          // 256 (s,o) pairs per block, 64 per wave
    const int sl = idx >> 4, ol = idx & 15;
    const int o = o0 + ol;
    const float* wrow = &wkv[(long)o << 10];
    const float* crow = &ctx[((long)(b * 64 + s0 + sl)) << 10];
    float a = 0.f;
#pragma unroll
    for (int i = 0; i < 4; ++i) {
      const f32x4 wv = *(const f32x4*)&wrow[lane * 4 + i * 256];
      const f32x4 cv = *(const f32x4*)&crow[lane * 4 + i * 256];
      a += wv[0] * cv[0] + wv[1] * cv[1] + wv[2] * cv[2] + wv[3] * cv[3];
    }
    a += __shfl_xor(a, 1);  a += __shfl_xor(a, 2);  a += __shfl_xor(a, 4);
    a += __shfl_xor(a, 8);  a += __shfl_xor(a, 16); a += __shfl_xor(a, 32);
    if (lane == 0) {
      const float r = a + bkv[o];
      if (o < 512) kT[(((long)b * 512 + o) << 6) + s0 + sl] = r;
      else         vOut[(((long)b * 64 + s0 + sl) << 9) + (o - 512)] = r;
    }
  }
}

// ---------------------------------------------------------------------------
// 5) Split-f16 TN GEMM: C[m][n] = sum_k A[m][k]*B[n][k] (+bias)(+residual)
//    A,B given as hi/lo f16 pairs; 3-term MFMA (hi*hi + hi*lo + lo*hi).
//    128x128x32 tiles, 4 waves (2x2 of 64x64), global_load_lds staging.
// ---------------------------------------------------------------------------
#define BM 128
#define BN 128
#define BK 32

template <int BIAS_PER_N, int RESID>
__global__ __launch_bounds__(256) void gemm_tn(
    const _Float16* __restrict__ Ahi, const _Float16* __restrict__ Alo,
    const _Float16* __restrict__ Bhi, const _Float16* __restrict__ Blo,
    float* __restrict__ C, const float* __restrict__ bias, const float* __restrict__ resid,
    int K, int lda, int ldb, int ldc,
    long aBatch, long bBatch, long cBatch, long rBatch)
{
  __shared__ _Float16 sA[2][BM * BK];
  __shared__ _Float16 sB[2][BN * BK];
  const int tid = threadIdx.x;
  const int lane = tid & 63;
  const int w = tid >> 6;
  const int bz = blockIdx.z;
  const long m0 = (long)blockIdx.x * BM;
  const long n0 = (long)blockIdx.y * BN;
  const _Float16* pAhi = Ahi + bz * aBatch + m0 * lda;
  const _Float16* pAlo = Alo + bz * aBatch + m0 * lda;
  const _Float16* pBhi = Bhi + bz * bBatch + n0 * ldb;
  const _Float16* pBlo = Blo + bz * bBatch + n0 * ldb;
  const int srow = lane >> 2;             // 0..15 rows per 1KB wave transfer
  const int schunk = (lane & 3) * 8;      // element offset of this lane's 16B
  const int wm = w >> 1, wn = w & 1;
  const int frow = lane & 15;
  const int fk = (lane >> 4) * 8;

  f32x4 acc[4][4] = {};

  for (int k0 = 0; k0 < K; k0 += BK) {
#pragma unroll
    for (int i = 0; i < 2; ++i) {
      const int r = w * 32 + i * 16 + srow;
      const int lbase = (w * 32 + i * 16) * BK;     // wave-uniform LDS base
      const long goa = (long)r * lda + k0 + schunk;
      gload_lds16(pAhi + goa, &sA[0][lbase]);
      gload_lds16(pAlo + goa, &sA[1][lbase]);
      const long gob = (long)r * ldb + k0 + schunk;
      gload_lds16(pBhi + gob, &sB[0][lbase]);
      gload_lds16(pBlo + gob, &sB[1][lbase]);
    }
    __syncthreads();
    half8 ah[4], al[4], bh[4], bl[4];
#pragma unroll
    for (int mi = 0; mi < 4; ++mi) {
      const int ro = (wm * 64 + mi * 16 + frow) * BK + fk;
      ah[mi] = *(const half8*)&sA[0][ro];
      al[mi] = *(const half8*)&sA[1][ro];
    }
#pragma unroll
    for (int ni = 0; ni < 4; ++ni) {
      const int ro = (wn * 64 + ni * 16 + frow) * BK + fk;
      bh[ni] = *(const half8*)&sB[0][ro];
      bl[ni] = *(const half8*)&sB[1][ro];
    }
#pragma unroll
    for (int mi = 0; mi < 4; ++mi) {
#pragma unroll
      for (int ni = 0; ni < 4; ++ni) {
        f32x4 a = acc[mi][ni];
        a = __builtin_amdgcn_mfma_f32_16x16x32_f16(al[mi], bh[ni], a, 0, 0, 0);
        a = __builtin_amdgcn_mfma_f32_16x16x32_f16(ah[mi], bl[ni], a, 0, 0, 0);
        a = __builtin_amdgcn_mfma_f32_16x16x32_f16(ah[mi], bh[ni], a, 0, 0, 0);
        acc[mi][ni] = a;
      }
    }
    __syncthreads();
  }

  const long cb = bz * cBatch;
  const long rb = bz * rBatch;
#pragma unroll
  for (int mi = 0; mi < 4; ++mi) {
#pragma unroll
    for (int ni = 0; ni < 4; ++ni) {
      const long row = m0 + wm * 64 + mi * 16 + (lane >> 4) * 4;
      const long col = n0 + wn * 64 + ni * 16 + (lane & 15);
#pragma unroll
      for (int j = 0; j < 4; ++j) {
        float v = acc[mi][ni][j];
        v += BIAS_PER_N ? bias[col] : bias[row + j];
        if (RESID) v += resid[rb + (row + j) * ldc + col];
        C[cb + (row + j) * ldc + col] = v;
      }
    }
  }
}

// ---------------------------------------------------------------------------
// 6) Block-causal cross-attention.
//    Block = (b, t, 64 queries). 256 threads: wave w owns s-range [16w,16w+16)
//    (wave-uniform causal skip), lane = query. Scores in registers; softmax
//    reduced across waves via LDS; PV per-wave c-slices; O written [p][c] hi/lo.
// ---------------------------------------------------------------------------
__global__ __launch_bounds__(256) void attn_kernel(const float* __restrict__ q,
                                                   const float* __restrict__ kT,
                                                   const float* __restrict__ v,
                                                   _Float16* __restrict__ Ohi,
                                                   _Float16* __restrict__ Olo)
{
  const int tid = threadIdx.x;
  const int lane = tid & 63;              // query within block
  const int w = tid >> 6;                 // wave = s-range / c-slice owner
  const int b = blockIdx.z, t = blockIdx.y;
  const int p = t * 1024 + blockIdx.x * 64 + lane;
  const int lim = min((t + 1) * 4, 64);   // valid context length
  __shared__ float buf[64 * 68];          // kT chunk [cc][s] then v chunk [s][c]
  __shared__ float wl[64 * 68];           // softmax weights [query][s]
  __shared__ float red[2][4][64];         // cross-wave max / sum
  const float* qrow = q + (((long)b * 16384 + p) << 9);

  float sc[16];
#pragma unroll
  for (int j = 0; j < 16; ++j) sc[j] = 0.f;

  // ---- QK^T ----
  for (int ch = 0; ch < 8; ++ch) {
#pragma unroll
    for (int i = 0; i < 4; ++i) {
      const int idx = tid + i * 256;
      const int cc = idx >> 4, s4 = (idx & 15) * 4;
      *(f32x4*)&buf[cc * 68 + s4] =
          *(const f32x4*)&kT[(((long)b * 512 + ch * 64 + cc) << 6) + s4];
    }
    __syncthreads();
    if (w * 16 < lim) {
#pragma unroll
      for (int cc4 = 0; cc4 < 16; ++cc4) {
        const f32x4 q4 = *(const f32x4*)&qrow[ch * 64 + cc4 * 4];
#pragma unroll
        for (int e = 0; e < 4; ++e) {
          const float qv = q4[e];
#pragma unroll
          for (int jj = 0; jj < 4; ++jj) {
            const f32x4 kk = *(const f32x4*)&buf[(cc4 * 4 + e) * 68 + w * 16 + jj * 4];
            sc[jj * 4 + 0] += qv * kk[0];
            sc[jj * 4 + 1] += qv * kk[1];
            sc[jj * 4 + 2] += qv * kk[2];
            sc[jj * 4 + 3] += qv * kk[3];
          }
        }
      }
    }
    __syncthreads();
  }

  // ---- softmax (max/sum reduced across the 4 waves) ----
  const float SCALE = 0.04419417382415922f;   // 1/sqrt(512)
  float m = -1e30f;
#pragma unroll
  for (int j = 0; j < 16; ++j) {
    sc[j] *= SCALE;
    if (w * 16 + j < lim) m = fmaxf(m, sc[j]);
  }
  red[0][w][lane] = m;
  __syncthreads();
  m = fmaxf(fmaxf(red[0][0][lane], red[0][1][lane]),
            fmaxf(red[0][2][lane], red[0][3][lane]));
  float sum = 0.f;
#pragma unroll
  for (int j = 0; j < 16; ++j) {
    const float e = (w * 16 + j < lim) ? __expf(sc[j] - m) : 0.f;
    sc[j] = e;
    sum += e;
  }
  red[1][w][lane] = sum;
  __syncthreads();
  sum = red[1][0][lane] + red[1][1][lane] + red[1][2][lane] + red[1][3][lane];
  const float inv = 1.f / sum;
#pragma unroll
  for (int j = 0; j < 16; ++j) wl[lane * 68 + w * 16 + j] = sc[j] * inv;
  __syncthreads();

  float wr[64];
#pragma unroll
  for (int s4 = 0; s4 < 16; ++s4) {
    const f32x4 wv = *(const f32x4*)&wl[lane * 68 + s4 * 4];
    wr[s4 * 4 + 0] = wv[0]; wr[s4 * 4 + 1] = wv[1];
    wr[s4 * 4 + 2] = wv[2]; wr[s4 * 4 + 3] = wv[3];
  }

  // ---- PV ----
  const long obase0 = (((long)b * 16384 + p) << 9) + w * 16;
  for (int ch = 0; ch < 8; ++ch) {
#pragma unroll
    for (int i = 0; i < 4; ++i) {
      const int idx = tid + i * 256;
      const int s = idx >> 4, c4 = (idx & 15) * 4;
      *(f32x4*)&buf[s * 68 + c4] =
          *(const f32x4*)&v[(((long)b * 64 + s) << 9) + ch * 64 + c4];
    }
    __syncthreads();
    float oa[16];
#pragma unroll
    for (int j = 0; j < 16; ++j) oa[j] = 0.f;
#pragma unroll
    for (int s4 = 0; s4 < 16; ++s4) {
      if (s4 * 4 < lim) {
#pragma unroll
        for (int e = 0; e < 4; ++e) {
          const float ws = wr[s4 * 4 + e];
#pragma unroll
          for (int c4 = 0; c4 < 4; ++c4) {
            const f32x4 vv = *(const f32x4*)&buf[(s4 * 4 + e) * 68 + w * 16 + c4 * 4];
            oa[c4 * 4 + 0] += ws * vv[0];
            oa[c4 * 4 + 1] += ws * vv[1];
            oa[c4 * 4 + 2] += ws * vv[2];
            oa[c4 * 4 + 3] += ws * vv[3];
          }
        }
      }
    }
    __syncthreads();
    half8 h0, h1, l0, l1;
#pragma unroll
    for (int j = 0; j < 16; ++j) {
      const _Float16 hi = (_Float16)oa[j];
      const _Float16 lo = (_Float16)(oa[j] - (float)hi);
      if (j < 8) { h0[j] = hi; l0[j] = lo; } else { h1[j - 8] = hi; l1[j - 8] = lo; }
    }
    *(half8*)&Ohi[obase0 + ch * 64]     = h0;
    *(half8*)&Ohi[obase0 + ch * 64 + 8] = h1;
    *(half8*)&Olo[obase0 + ch * 64]     = l0;
    *(half8*)&Olo[obase0 + ch * 64 + 8] = l1;
  }
}

// ---------------------------------------------------------------------------
// launcher
// ---------------------------------------------------------------------------
extern "C" void kernel_launch(void* const* d_in, const int* in_sizes, int n_in,
                              void* d_out, int out_size, void* d_ws, size_t ws_size,
                              hipStream_t stream)
{
  (void)in_sizes; (void)n_in; (void)out_size; (void)ws_size;
  const float* x     = (const float*)d_in[0];
  const float* ctx   = (const float*)d_in[1];
  const float* gamma = (const float*)d_in[2];
  const float* beta  = (const float*)d_in[3];
  const float* wq    = (const float*)d_in[4];
  const float* bq    = (const float*)d_in[5];
  const float* wkv   = (const float*)d_in[6];
  const float* bkv   = (const float*)d_in[7];
  const float* wo    = (const float*)d_in[8];
  const float* bo    = (const float*)d_in[9];
  float* out = (float*)d_out;

  char* ws = (char*)d_ws;
  size_t off = 0;
  auto alloc = [&](size_t bytes) -> void* {
    void* p = ws + off;
    off += (bytes + 255) & ~(size_t)255;
    return p;
  };
  const long HPC = 8388608;                       // 16384 * 512 elements per batch
  _Float16* hHi  = (_Float16*)alloc(2 * HPC * 2); // [b][p][c] f16 hi
  _Float16* hLo  = (_Float16*)alloc(2 * HPC * 2);
  float*    qArr = (float*)alloc(2 * HPC * 4);    // [b][p][o] f32
  _Float16* wqHi = (_Float16*)alloc(512 * 512 * 2);
  _Float16* wqLo = (_Float16*)alloc(512 * 512 * 2);
  _Float16* woHi = (_Float16*)alloc(512 * 512 * 2);
  _Float16* woLo = (_Float16*)alloc(512 * 512 * 2);
  float*    kT   = (float*)alloc(2 * 512 * 64 * 4);
  float*    vB   = (float*)alloc(2 * 64 * 512 * 4);
  float*    muA  = (float*)alloc(1024 * 4);
  float*    rsA  = (float*)alloc(1024 * 4);
  _Float16* oHi  = hHi;                           // h dead after q-GEMM: reuse for O
  _Float16* oLo  = hLo;

  gn_stats<<<dim3(16, 32, 2), 256, 0, stream>>>(x, muA, rsA);
  gn_apply<<<dim3(256, 8, 2), 256, 0, stream>>>(x, muA, rsA, gamma, beta, hHi, hLo);
  split_w<<<dim3(256), 256, 0, stream>>>(wq, wqHi, wqLo, 65536);
  split_w<<<dim3(256), 256, 0, stream>>>(wo, woHi, woLo, 65536);
  kv_proj<<<dim3(64, 4, 2), 256, 0, stream>>>(ctx, wkv, bkv, kT, vB);

  // q[b][p][o] = h[b][p][:] . wq[o][:] + bq[o]
  gemm_tn<1, 0><<<dim3(128, 4, 2), 256, 0, stream>>>(
      hHi, hLo, wqHi, wqLo, qArr, bq, nullptr,
      512, 512, 512, 512, HPC, 0, HPC, 0);

  attn_kernel<<<dim3(16, 16, 2), 256, 0, stream>>>(qArr, kT, vB, oHi, oLo);

  // out[b][o][p] = x[b][o][p] + O[b][p][:] . wo[o][:] + bo[o]
  gemm_tn<0, 1><<<dim3(4, 128, 2), 256, 0, stream>>>(
      woHi, woLo, oHi, oLo, out, bo, x,
      512, 512, 512, 16384, 0, HPC, HPC, HPC);
}

// Round 2
// 300.961 us; speedup vs baseline: 1.4459x; 1.4459x over previous
//
#include <hip/hip_runtime.h>

// ---------------------------------------------------------------------------
// CausalCrossAttention — pure-f16 MFMA pipeline
// B=2 C=512 T=16 H=W=32 (P=16384/batch), S=64 D=1024, groups=32.
// gn_stats -> gn_apply(h f16) -> [wq,wo->f16] kv mini-GEMM(k,vT f16)
//   -> q-GEMM(f16) -> barrier-free MFMA attention -> o-GEMM(f16,+bias+resid)
// ---------------------------------------------------------------------------

typedef float    f32x4 __attribute__((ext_vector_type(4)));
typedef _Float16 half8 __attribute__((ext_vector_type(8)));
typedef _Float16 half4 __attribute__((ext_vector_type(4)));

#define GLB_AS __attribute__((address_space(1)))
#define LDS_AS __attribute__((address_space(3)))

__device__ __forceinline__ void gload_lds16(const void* g, void* l) {
  __builtin_amdgcn_global_load_lds((const GLB_AS void*)g, (LDS_AS void*)l, 16, 0, 0);
}

// ---------------------------------------------------------------------------
// 1) GroupNorm statistics: one block per (b, g, t)
// ---------------------------------------------------------------------------
__global__ __launch_bounds__(256) void gn_stats(const float* __restrict__ x,
                                                float* __restrict__ muA,
                                                float* __restrict__ rsA)
{
  const int t = blockIdx.x, g = blockIdx.y, b = blockIdx.z;
  const int tid = threadIdx.x;
  float s1 = 0.f, s2 = 0.f;
#pragma unroll
  for (int c = 0; c < 16; ++c) {
    const long base = (((long)(b * 512 + g * 16 + c) * 16 + t) << 10) + tid * 4;
    const f32x4 v = *(const f32x4*)&x[base];
    s1 += v[0] + v[1] + v[2] + v[3];
    s2 += v[0] * v[0] + v[1] * v[1] + v[2] * v[2] + v[3] * v[3];
  }
  for (int o = 32; o; o >>= 1) { s1 += __shfl_down(s1, o); s2 += __shfl_down(s2, o); }
  __shared__ float r1[4], r2[4];
  const int w = tid >> 6;
  if ((tid & 63) == 0) { r1[w] = s1; r2[w] = s2; }
  __syncthreads();
  if (tid == 0) {
    const float a = r1[0] + r1[1] + r1[2] + r1[3];
    const float q = r2[0] + r2[1] + r2[2] + r2[3];
    const float mu = a * (1.f / 16384.f);
    const float var = q * (1.f / 16384.f) - mu * mu;
    const int idx = (b * 32 + g) * 16 + t;
    muA[idx] = mu;
    rsA[idx] = 1.f / sqrtf(var + 1e-5f);
  }
}

// ---------------------------------------------------------------------------
// 2) Apply GN + transpose x[b][c][p] -> h[b][p][c] f16
// ---------------------------------------------------------------------------
__global__ __launch_bounds__(256) void gn_apply(const float* __restrict__ x,
                                                const float* __restrict__ muA,
                                                const float* __restrict__ rsA,
                                                const float* __restrict__ gamma,
                                                const float* __restrict__ beta,
                                                _Float16* __restrict__ h)
{
  const int b = blockIdx.z;
  const int c0 = blockIdx.y * 64;
  const int p0 = blockIdx.x * 64;
  const int t = p0 >> 10;                 // 64-wide p tile never crosses a frame
  __shared__ float tile[64 * 65];
  const int tid = threadIdx.x;
  const int rr = tid >> 4;
  const int col4 = (tid & 15) * 4;
#pragma unroll
  for (int i = 0; i < 4; ++i) {
    const int r = i * 16 + rr;
    const int c = c0 + r;
    const int gi = (b * 32 + (c >> 4)) * 16 + t;
    const float s = rsA[gi] * gamma[c];
    const float o = beta[c] - muA[gi] * s;
    const f32x4 v = *(const f32x4*)&x[(((long)b * 512 + c) << 14) + p0 + col4];
    tile[r * 65 + col4 + 0] = v[0] * s + o;
    tile[r * 65 + col4 + 1] = v[1] * s + o;
    tile[r * 65 + col4 + 2] = v[2] * s + o;
    tile[r * 65 + col4 + 3] = v[3] * s + o;
  }
  __syncthreads();
  const int pr = tid >> 2;
  const int cs = (tid & 3) * 16;
  const long obase = (((long)b * 16384 + p0 + pr) << 9) + c0 + cs;
  half8 h0, h1;
#pragma unroll
  for (int j = 0; j < 16; ++j) {
    const _Float16 hi = (_Float16)tile[(cs + j) * 65 + pr];
    if (j < 8) h0[j] = hi; else h1[j - 8] = hi;
  }
  *(half8*)&h[obase]     = h0;
  *(half8*)&h[obase + 8] = h1;
}

// ---------------------------------------------------------------------------
// 3) f32 -> f16 conversion (weights)
// ---------------------------------------------------------------------------
__global__ void to_f16(const float* __restrict__ src, _Float16* __restrict__ dst, int n4)
{
  const int i = blockIdx.x * blockDim.x + threadIdx.x;
  if (i >= n4) return;
  const f32x4 v = *(const f32x4*)&src[i * 4];
  half4 hh;
#pragma unroll
  for (int j = 0; j < 4; ++j) hh[j] = (_Float16)v[j];
  *(half4*)&dst[i * 4] = hh;
}

// ---------------------------------------------------------------------------
// 4) kv mini-GEMM: kv[b,s,o] = ctx[b,s,:].wkv[o,:] + bkv[o]
//    block = (o-chunk of 16, b); wave w owns o = o0+4w..+4, lane = s.
//    k -> f16 [b][s][c]; v -> f16 transposed vT [b][c][s].
// ---------------------------------------------------------------------------
__global__ __launch_bounds__(256) void kv_gemm(const float* __restrict__ ctx,
                                               const float* __restrict__ wkv,
                                               const float* __restrict__ bkv,
                                               _Float16* __restrict__ kOut,
                                               _Float16* __restrict__ vT)
{
  const int b = blockIdx.y;
  const int o0 = blockIdx.x * 16;
  const int tid = threadIdx.x, l = tid & 63, w = tid >> 6;
  __shared__ float cbuf[64 * 64];   // ctx chunk [s][d], XOR-16B swizzled
  __shared__ float wbuf[16 * 64];   // wkv chunk [o][d], linear (broadcast reads)
  float acc[4] = {0.f, 0.f, 0.f, 0.f};

  for (int dc = 0; dc < 16; ++dc) {
#pragma unroll
    for (int i = 0; i < 4; ++i) {   // stage ctx 64x64
      const int lin = tid + i * 256;
      const int s = lin >> 4, c4 = lin & 15;
      *(f32x4*)&cbuf[s * 64 + ((c4 ^ (s & 15)) << 2)] =
          *(const f32x4*)&ctx[((long)(b * 64 + s) << 10) + dc * 64 + c4 * 4];
    }
    {                               // stage wkv 16x64
      const int o = tid >> 4, c4 = tid & 15;
      *(f32x4*)&wbuf[o * 64 + c4 * 4] =
          *(const f32x4*)&wkv[((long)(o0 + o) << 10) + dc * 64 + c4 * 4];
    }
    __syncthreads();
#pragma unroll
    for (int d4 = 0; d4 < 16; ++d4) {
      const f32x4 cv = *(const f32x4*)&cbuf[l * 64 + ((d4 ^ (l & 15)) << 2)];
#pragma unroll
      for (int j = 0; j < 4; ++j) {
        const f32x4 wv = *(const f32x4*)&wbuf[(w * 4 + j) * 64 + (d4 << 2)];
        acc[j] += cv[0] * wv[0] + cv[1] * wv[1] + cv[2] * wv[2] + cv[3] * wv[3];
      }
    }
    __syncthreads();
  }
#pragma unroll
  for (int j = 0; j < 4; ++j) {
    const int o = o0 + w * 4 + j;
    const float r = acc[j] + bkv[o];
    if (o < 512) kOut[((long)(b * 64 + l) << 9) + o] = (_Float16)r;
    else         vT[((long)(b * 512 + (o - 512)) << 6) + l] = (_Float16)r;
  }
}

// ---------------------------------------------------------------------------
// 5) f16 TN GEMM: C[m][n] = sum_k A[m][k]*B[n][k] (+bias)(+resid)
//    128x128x32 tiles, 4 waves (2x2 of 64x64), global_load_lds staging.
// ---------------------------------------------------------------------------
#define BM 128
#define BN 128
#define BK 32

template <int BIAS_PER_N, int RESID, int OUT16>
__global__ __launch_bounds__(256) void gemm_f16(
    const _Float16* __restrict__ A, const _Float16* __restrict__ B,
    void* __restrict__ Cv, const float* __restrict__ bias, const float* __restrict__ resid,
    int K, int lda, int ldb, int ldc,
    long aBatch, long bBatch, long cBatch, long rBatch)
{
  __shared__ _Float16 sA[BM * BK];
  __shared__ _Float16 sB[BN * BK];
  const int tid = threadIdx.x;
  const int lane = tid & 63;
  const int w = tid >> 6;
  const int bz = blockIdx.z;
  const long m0 = (long)blockIdx.x * BM;
  const long n0 = (long)blockIdx.y * BN;
  const _Float16* pA = A + bz * aBatch + m0 * lda;
  const _Float16* pB = B + bz * bBatch + n0 * ldb;
  const int srow = lane >> 2;
  const int schunk = (lane & 3) * 8;
  const int wm = w >> 1, wn = w & 1;
  const int frow = lane & 15;
  const int fk = (lane >> 4) * 8;

  f32x4 acc[4][4] = {};

  for (int k0 = 0; k0 < K; k0 += BK) {
#pragma unroll
    for (int i = 0; i < 2; ++i) {
      const int r = w * 32 + i * 16 + srow;
      const int lbase = (w * 32 + i * 16) * BK;
      gload_lds16(pA + (long)r * lda + k0 + schunk, &sA[lbase]);
      gload_lds16(pB + (long)r * ldb + k0 + schunk, &sB[lbase]);
    }
    __syncthreads();
    half8 ah[4], bh[4];
#pragma unroll
    for (int mi = 0; mi < 4; ++mi)
      ah[mi] = *(const half8*)&sA[(wm * 64 + mi * 16 + frow) * BK + fk];
#pragma unroll
    for (int ni = 0; ni < 4; ++ni)
      bh[ni] = *(const half8*)&sB[(wn * 64 + ni * 16 + frow) * BK + fk];
#pragma unroll
    for (int mi = 0; mi < 4; ++mi)
#pragma unroll
      for (int ni = 0; ni < 4; ++ni)
        acc[mi][ni] = __builtin_amdgcn_mfma_f32_16x16x32_f16(ah[mi], bh[ni], acc[mi][ni], 0, 0, 0);
    __syncthreads();
  }

  const long cb = bz * cBatch;
  const long rb = bz * rBatch;
#pragma unroll
  for (int mi = 0; mi < 4; ++mi) {
#pragma unroll
    for (int ni = 0; ni < 4; ++ni) {
      const long row = m0 + wm * 64 + mi * 16 + (lane >> 4) * 4;
      const long col = n0 + wn * 64 + ni * 16 + (lane & 15);
#pragma unroll
      for (int j = 0; j < 4; ++j) {
        float v = acc[mi][ni][j];
        v += BIAS_PER_N ? bias[col] : bias[row + j];
        if (RESID) v += resid[rb + (row + j) * ldc + col];
        if (OUT16) ((_Float16*)Cv)[cb + (row + j) * ldc + col] = (_Float16)v;
        else       ((float*)Cv)[cb + (row + j) * ldc + col] = v;
      }
    }
  }
}

// ---------------------------------------------------------------------------
// 6) Barrier-free MFMA attention.
//    Block = (b, t, 64-query chunk); 4 independent waves, wave = 16 queries.
//    QK^T via mfma 16x16x32 (q/k frags straight from global; k,vT are L2-hot),
//    in-register softmax (16-lane shfl group), weights -> 2KB per-wave LDS,
//    PV against vT[c][s] in two 256-c halves. Zero __syncthreads.
// ---------------------------------------------------------------------------
__global__ __launch_bounds__(256) void attn2(const _Float16* __restrict__ q,   // [b][p][c]
                                             const _Float16* __restrict__ k,   // [b][s][c]
                                             const _Float16* __restrict__ vT,  // [b][c][s]
                                             _Float16* __restrict__ O)         // [b][p][c]
{
  const int tid = threadIdx.x;
  const int l = tid & 63, w = tid >> 6;
  const int b = blockIdx.z, t = blockIdx.y;
  const int p0 = t * 1024 + blockIdx.x * 64 + w * 16;  // wave's 16 query rows
  const int lim = (t + 1) * 4;
  const int nf = (t >> 2) + 1;          // ceil(lim/16)
  const int ks = (t >> 3) + 1;          // ceil(lim/32)
  const int cl = l & 15;
  const int g8 = (l >> 4) * 8;
  const int r4 = (l >> 4) * 4;

  __shared__ _Float16 wlds[4][16][72];  // per-wave softmax weights, padded rows

  // ---- QK^T ----
  f32x4 sc[4] = {};
  const _Float16* qb = q + (((long)(b * 16384 + p0 + cl)) << 9) + g8;
  const _Float16* kb = k + (((long)(b * 64 + cl)) << 9) + g8;
#pragma unroll
  for (int kk = 0; kk < 16; ++kk) {
    const half8 af = *(const half8*)(qb + kk * 32);
#pragma unroll
    for (int f = 0; f < 4; ++f)
      if (f < nf)
        sc[f] = __builtin_amdgcn_mfma_f32_16x16x32_f16(
            af, *(const half8*)(kb + f * (16 * 512) + kk * 32), sc[f], 0, 0, 0);
  }

  // ---- softmax (rows r4..r4+3, cols cl+16f; reduce across 16-lane group) ----
  const float SCALE = 0.044194173824159216f;   // 1/sqrt(512)
  float ex[4][4], mj[4], sj[4];
#pragma unroll
  for (int j = 0; j < 4; ++j) {
    float mx = -1e30f;
#pragma unroll
    for (int f = 0; f < 4; ++f) {
      float v = sc[f][j] * SCALE;
      if (f * 16 + cl >= lim) v = -1e30f;   // also covers f >= nf (sc==0 there)
      ex[f][j] = v;
      mx = fmaxf(mx, v);
    }
    mj[j] = mx;
  }
#pragma unroll
  for (int o = 1; o < 16; o <<= 1)
#pragma unroll
    for (int j = 0; j < 4; ++j) mj[j] = fmaxf(mj[j], __shfl_xor(mj[j], o));
#pragma unroll
  for (int j = 0; j < 4; ++j) {
    float s = 0.f;
#pragma unroll
    for (int f = 0; f < 4; ++f) {
      const float e = __expf(ex[f][j] - mj[j]);  // masked -> 0
      ex[f][j] = e;
      s += e;
    }
    sj[j] = s;
  }
#pragma unroll
  for (int o = 1; o < 16; o <<= 1)
#pragma unroll
    for (int j = 0; j < 4; ++j) sj[j] += __shfl_xor(sj[j], o);
#pragma unroll
  for (int j = 0; j < 4; ++j) {
    const float inv = 1.f / sj[j];
#pragma unroll
    for (int f = 0; f < 4; ++f)
      wlds[w][r4 + j][f * 16 + cl] = (_Float16)(ex[f][j] * inv);  // all 64 s written
  }

  // ---- PV: O[16q x 512c] in two 256-c halves ----
  const half8 wa0 = *(const half8*)&wlds[w][cl][g8];
  const half8 wa1 = *(const half8*)&wlds[w][cl][32 + g8];
#pragma unroll
  for (int hf = 0; hf < 2; ++hf) {
    f32x4 oc[16] = {};
#pragma unroll
    for (int cf = 0; cf < 16; ++cf) {
      const _Float16* vb = vT + (((long)(b * 512 + hf * 256 + cf * 16 + cl)) << 6) + g8;
      oc[cf] = __builtin_amdgcn_mfma_f32_16x16x32_f16(wa0, *(const half8*)vb, oc[cf], 0, 0, 0);
      if (ks == 2)
        oc[cf] = __builtin_amdgcn_mfma_f32_16x16x32_f16(wa1, *(const half8*)(vb + 32), oc[cf], 0, 0, 0);
    }
#pragma unroll
    for (int cf = 0; cf < 16; ++cf)
#pragma unroll
      for (int j = 0; j < 4; ++j)
        O[(((long)(b * 16384 + p0 + r4 + j)) << 9) + hf * 256 + cf * 16 + cl] =
            (_Float16)oc[cf][j];
  }
}

// ---------------------------------------------------------------------------
// launcher
// ---------------------------------------------------------------------------
extern "C" void kernel_launch(void* const* d_in, const int* in_sizes, int n_in,
                              void* d_out, int out_size, void* d_ws, size_t ws_size,
                              hipStream_t stream)
{
  (void)in_sizes; (void)n_in; (void)out_size; (void)ws_size;
  const float* x     = (const float*)d_in[0];
  const float* ctx   = (const float*)d_in[1];
  const float* gamma = (const float*)d_in[2];
  const float* beta  = (const float*)d_in[3];
  const float* wq    = (const float*)d_in[4];
  const float* bq    = (const float*)d_in[5];
  const float* wkv   = (const float*)d_in[6];
  const float* bkv   = (const float*)d_in[7];
  const float* wo    = (const float*)d_in[8];
  const float* bo    = (const float*)d_in[9];
  float* out = (float*)d_out;

  char* ws = (char*)d_ws;
  size_t off = 0;
  auto alloc = [&](size_t bytes) -> void* {
    void* p = ws + off;
    off += (bytes + 255) & ~(size_t)255;
    return p;
  };
  const long HPC = 8388608;                        // 16384*512 per batch
  _Float16* hF   = (_Float16*)alloc(2 * HPC * 2);  // h [b][p][c] f16 (reused for O)
  _Float16* qF   = (_Float16*)alloc(2 * HPC * 2);  // q [b][p][c] f16
  _Float16* wqF  = (_Float16*)alloc(512 * 512 * 2);
  _Float16* woF  = (_Float16*)alloc(512 * 512 * 2);
  _Float16* kF   = (_Float16*)alloc(2 * 64 * 512 * 2);   // k [b][s][c]
  _Float16* vTF  = (_Float16*)alloc(2 * 512 * 64 * 2);   // vT [b][c][s]
  float*    muA  = (float*)alloc(1024 * 4);
  float*    rsA  = (float*)alloc(1024 * 4);
  _Float16* oF   = hF;                             // h dead after q-GEMM

  gn_stats<<<dim3(16, 32, 2), 256, 0, stream>>>(x, muA, rsA);
  gn_apply<<<dim3(256, 8, 2), 256, 0, stream>>>(x, muA, rsA, gamma, beta, hF);
  to_f16<<<dim3(256), 256, 0, stream>>>(wq, wqF, 65536);
  to_f16<<<dim3(256), 256, 0, stream>>>(wo, woF, 65536);
  kv_gemm<<<dim3(64, 2), 256, 0, stream>>>(ctx, wkv, bkv, kF, vTF);

  // q[b][p][o] = h[b][p][:].wq[o][:] + bq[o]  (f16 out)
  gemm_f16<1, 0, 1><<<dim3(128, 4, 2), 256, 0, stream>>>(
      hF, wqF, qF, bq, nullptr, 512, 512, 512, 512, HPC, 0, HPC, 0);

  attn2<<<dim3(16, 16, 2), 256, 0, stream>>>(qF, kF, vTF, oF);

  // out[b][o][p] = x[b][o][p] + O[b][p][:].wo[o][:] + bo[o]  (f32 out)
  gemm_f16<0, 1, 0><<<dim3(4, 128, 2), 256, 0, stream>>>(
      woF, oF, out, bo, x, 512, 512, 512, 16384, 0, HPC, HPC, HPC);
}

// Round 3
// 291.368 us; speedup vs baseline: 1.4935x; 1.0329x over previous
//
#include <hip/hip_runtime.h>

// ---------------------------------------------------------------------------
// CausalCrossAttention — pure-f16 MFMA pipeline, round 3
// B=2 C=512 T=16 H=W=32 (P=16384/batch), S=64 D=1024, groups=32.
// gn_fused(h f16) -> [wq,wo->f16] kv mini-GEMM(k,vT f16)
//   -> q-GEMM(f16, 2-phase prefetch, XCD swizzle) -> barrier-free MFMA attn
//   -> o-GEMM(f16->f32, +bias+resid, 2-phase prefetch, XCD swizzle)
// ---------------------------------------------------------------------------

typedef float    f32x4 __attribute__((ext_vector_type(4)));
typedef _Float16 half8 __attribute__((ext_vector_type(8)));
typedef _Float16 half4 __attribute__((ext_vector_type(4)));

#define GLB_AS __attribute__((address_space(1)))
#define LDS_AS __attribute__((address_space(3)))

__device__ __forceinline__ void gload_lds16(const void* g, void* l) {
  __builtin_amdgcn_global_load_lds((const GLB_AS void*)g, (LDS_AS void*)l, 16, 0, 0);
}

// ---------------------------------------------------------------------------
// 1) Fused GroupNorm: block = (b, g, t) owns 16 ch x 1024 px (64 KB).
//    Stage x in LDS [c][1028] (b128 conflict-free writes), block-reduce
//    mean/var, apply + transpose -> h[b][p][c] f16. x read ONCE from HBM.
// ---------------------------------------------------------------------------
__global__ __launch_bounds__(256) void gn_fused(const float* __restrict__ x,
                                                const float* __restrict__ gamma,
                                                const float* __restrict__ beta,
                                                _Float16* __restrict__ h)
{
  const int t = blockIdx.x, g = blockIdx.y, b = blockIdx.z;
  const int tid = threadIdx.x;
  __shared__ float tile[16 * 1028];
  __shared__ float red[2][4];
  const long xbase = ((long)((b * 512 + g * 16) * 16 + t)) << 10;

  float s1 = 0.f, s2 = 0.f;
#pragma unroll
  for (int i = 0; i < 16; ++i) {
    const int idx = i * 256 + tid;
    const int c = idx >> 8;
    const int p = (idx & 255) * 4;
    const f32x4 v = *(const f32x4*)&x[xbase + ((long)c << 14) + p];
    s1 += v[0] + v[1] + v[2] + v[3];
    s2 += v[0] * v[0] + v[1] * v[1] + v[2] * v[2] + v[3] * v[3];
    *(f32x4*)&tile[c * 1028 + p] = v;
  }
  for (int o = 32; o; o >>= 1) { s1 += __shfl_down(s1, o); s2 += __shfl_down(s2, o); }
  if ((tid & 63) == 0) { red[0][tid >> 6] = s1; red[1][tid >> 6] = s2; }
  __syncthreads();
  const float a  = red[0][0] + red[0][1] + red[0][2] + red[0][3];
  const float qq = red[1][0] + red[1][1] + red[1][2] + red[1][3];
  const float mu = a * (1.f / 16384.f);
  const float rs = rsqrtf(qq * (1.f / 16384.f) - mu * mu + 1e-5f);

  float scv[16], ocv[16];
#pragma unroll
  for (int c4 = 0; c4 < 4; ++c4) {
    const f32x4 gv = *(const f32x4*)&gamma[g * 16 + c4 * 4];
    const f32x4 bv = *(const f32x4*)&beta[g * 16 + c4 * 4];
#pragma unroll
    for (int j = 0; j < 4; ++j) {
      scv[c4 * 4 + j] = rs * gv[j];
      ocv[c4 * 4 + j] = bv[j] - mu * scv[c4 * 4 + j];
    }
  }

  const long hbase = (((long)b * 16384 + (long)t * 1024) << 9) + g * 16;
#pragma unroll
  for (int it = 0; it < 4; ++it) {
    const int p = it * 256 + tid;
    half8 h0, h1;
#pragma unroll
    for (int c = 0; c < 16; ++c) {
      const _Float16 hv = (_Float16)(tile[c * 1028 + p] * scv[c] + ocv[c]);
      if (c < 8) h0[c] = hv; else h1[c - 8] = hv;
    }
    *(half8*)&h[hbase + (long)p * 512]     = h0;
    *(half8*)&h[hbase + (long)p * 512 + 8] = h1;
  }
}

// ---------------------------------------------------------------------------
// 2) f32 -> f16 conversion (weights)
// ---------------------------------------------------------------------------
__global__ void to_f16(const float* __restrict__ src, _Float16* __restrict__ dst, int n4)
{
  const int i = blockIdx.x * blockDim.x + threadIdx.x;
  if (i >= n4) return;
  const f32x4 v = *(const f32x4*)&src[i * 4];
  half4 hh;
#pragma unroll
  for (int j = 0; j < 4; ++j) hh[j] = (_Float16)v[j];
  *(half4*)&dst[i * 4] = hh;
}

// ---------------------------------------------------------------------------
// 3) kv mini-GEMM: kv[b,s,o] = ctx[b,s,:].wkv[o,:] + bkv[o]
//    k -> f16 [b][s][c]; v -> f16 transposed vT [b][c][s].
// ---------------------------------------------------------------------------
__global__ __launch_bounds__(256) void kv_gemm(const float* __restrict__ ctx,
                                               const float* __restrict__ wkv,
                                               const float* __restrict__ bkv,
                                               _Float16* __restrict__ kOut,
                                               _Float16* __restrict__ vT)
{
  const int b = blockIdx.y;
  const int o0 = blockIdx.x * 16;
  const int tid = threadIdx.x, l = tid & 63, w = tid >> 6;
  __shared__ float cbuf[64 * 64];   // ctx chunk [s][d], XOR-16B swizzled
  __shared__ float wbuf[16 * 64];   // wkv chunk [o][d], linear (broadcast reads)
  float acc[4] = {0.f, 0.f, 0.f, 0.f};

  for (int dc = 0; dc < 16; ++dc) {
#pragma unroll
    for (int i = 0; i < 4; ++i) {
      const int lin = tid + i * 256;
      const int s = lin >> 4, c4 = lin & 15;
      *(f32x4*)&cbuf[s * 64 + ((c4 ^ (s & 15)) << 2)] =
          *(const f32x4*)&ctx[((long)(b * 64 + s) << 10) + dc * 64 + c4 * 4];
    }
    {
      const int o = tid >> 4, c4 = tid & 15;
      *(f32x4*)&wbuf[o * 64 + c4 * 4] =
          *(const f32x4*)&wkv[((long)(o0 + o) << 10) + dc * 64 + c4 * 4];
    }
    __syncthreads();
#pragma unroll
    for (int d4 = 0; d4 < 16; ++d4) {
      const f32x4 cv = *(const f32x4*)&cbuf[l * 64 + ((d4 ^ (l & 15)) << 2)];
#pragma unroll
      for (int j = 0; j < 4; ++j) {
        const f32x4 wv = *(const f32x4*)&wbuf[(w * 4 + j) * 64 + (d4 << 2)];
        acc[j] += cv[0] * wv[0] + cv[1] * wv[1] + cv[2] * wv[2] + cv[3] * wv[3];
      }
    }
    __syncthreads();
  }
#pragma unroll
  for (int j = 0; j < 4; ++j) {
    const int o = o0 + w * 4 + j;
    const float r = acc[j] + bkv[o];
    if (o < 512) kOut[((long)(b * 64 + l) << 9) + o] = (_Float16)r;
    else         vT[((long)(b * 512 + (o - 512)) << 6) + l] = (_Float16)r;
  }
}

// ---------------------------------------------------------------------------
// 4) f16 TN GEMM with 2-phase prefetch (double-buffered global_load_lds) and
//    XCD-chunked block swizzle. C[m][n] = sum_k A[m][k]*B[n][k] (+bias)(+resid)
//    SWZ=1: o-GEMM decode (m=nf&3, n=nf>>2); SWZ=2: q-GEMM (m=nf>>2, n=nf&3).
// ---------------------------------------------------------------------------
#define BM 128
#define BN 128
#define BK 32

template <int BIAS_PER_N, int RESID, int OUT16, int SWZ>
__global__ __launch_bounds__(256) void gemm_f16(
    const _Float16* __restrict__ A, const _Float16* __restrict__ B,
    void* __restrict__ Cv, const float* __restrict__ bias, const float* __restrict__ resid,
    int K, int lda, int ldb, int ldc,
    long aBatch, long bBatch, long cBatch, long rBatch)
{
  __shared__ _Float16 sA[2][BM * BK];
  __shared__ _Float16 sB[2][BN * BK];
  const int tid = threadIdx.x;
  const int lane = tid & 63;
  const int w = tid >> 6;
  const int bz = blockIdx.z;

  int bx, by;
  if (SWZ == 1) {        // 512 blocks: same-n m-group -> same XCD
    const int f = blockIdx.x;
    const int nf = ((f & 7) << 6) | (f >> 3);
    bx = nf & 3; by = nf >> 2;
  } else if (SWZ == 2) { // 512 blocks: same-m n-group -> same XCD
    const int f = blockIdx.x;
    const int nf = ((f & 7) << 6) | (f >> 3);
    bx = nf >> 2; by = nf & 3;
  } else {
    bx = blockIdx.x; by = blockIdx.y;
  }

  const long m0 = (long)bx * BM;
  const long n0 = (long)by * BN;
  const _Float16* pA = A + bz * aBatch + m0 * lda;
  const _Float16* pB = B + bz * bBatch + n0 * ldb;
  const int srow = lane >> 2;
  const int schunk = (lane & 3) * 8;
  const int wm = w >> 1, wn = w & 1;
  const int frow = lane & 15;
  const int fk = (lane >> 4) * 8;

  f32x4 acc[4][4] = {};

  auto stage = [&](int buf, int k0) {
#pragma unroll
    for (int i = 0; i < 2; ++i) {
      const int r = w * 32 + i * 16 + srow;
      const int lbase = (w * 32 + i * 16) * BK;
      gload_lds16(pA + (long)r * lda + k0 + schunk, &sA[buf][lbase]);
      gload_lds16(pB + (long)r * ldb + k0 + schunk, &sB[buf][lbase]);
    }
  };

  stage(0, 0);
  __syncthreads();            // compiler drains vmcnt(0) before s_barrier
  int cur = 0;
  for (int k0 = 0; k0 < K; k0 += BK) {
    if (k0 + BK < K) stage(cur ^ 1, k0 + BK);   // prefetch flies during MFMA
    half8 ah[4], bh[4];
#pragma unroll
    for (int mi = 0; mi < 4; ++mi)
      ah[mi] = *(const half8*)&sA[cur][(wm * 64 + mi * 16 + frow) * BK + fk];
#pragma unroll
    for (int ni = 0; ni < 4; ++ni)
      bh[ni] = *(const half8*)&sB[cur][(wn * 64 + ni * 16 + frow) * BK + fk];
#pragma unroll
    for (int mi = 0; mi < 4; ++mi)
#pragma unroll
      for (int ni = 0; ni < 4; ++ni)
        acc[mi][ni] = __builtin_amdgcn_mfma_f32_16x16x32_f16(ah[mi], bh[ni], acc[mi][ni], 0, 0, 0);
    __syncthreads();          // prefetch drained + all reads of cur done
    cur ^= 1;
  }

  const long cb = bz * cBatch;
  const long rb = bz * rBatch;
#pragma unroll
  for (int mi = 0; mi < 4; ++mi) {
#pragma unroll
    for (int ni = 0; ni < 4; ++ni) {
      const long row = m0 + wm * 64 + mi * 16 + (lane >> 4) * 4;
      const long col = n0 + wn * 64 + ni * 16 + (lane & 15);
#pragma unroll
      for (int j = 0; j < 4; ++j) {
        float v = acc[mi][ni][j];
        v += BIAS_PER_N ? bias[col] : bias[row + j];
        if (RESID) v += resid[rb + (row + j) * ldc + col];
        if (OUT16) ((_Float16*)Cv)[cb + (row + j) * ldc + col] = (_Float16)v;
        else       ((float*)Cv)[cb + (row + j) * ldc + col] = v;
      }
    }
  }
}

// ---------------------------------------------------------------------------
// 5) Barrier-free MFMA attention (unchanged from round 2).
// ---------------------------------------------------------------------------
__global__ __launch_bounds__(256) void attn2(const _Float16* __restrict__ q,   // [b][p][c]
                                             const _Float16* __restrict__ k,   // [b][s][c]
                                             const _Float16* __restrict__ vT,  // [b][c][s]
                                             _Float16* __restrict__ O)         // [b][p][c]
{
  const int tid = threadIdx.x;
  const int l = tid & 63, w = tid >> 6;
  const int b = blockIdx.z, t = blockIdx.y;
  const int p0 = t * 1024 + blockIdx.x * 64 + w * 16;
  const int lim = (t + 1) * 4;
  const int nf = (t >> 2) + 1;
  const int ks = (t >> 3) + 1;
  const int cl = l & 15;
  const int g8 = (l >> 4) * 8;
  const int r4 = (l >> 4) * 4;

  __shared__ _Float16 wlds[4][16][72];

  f32x4 sc[4] = {};
  const _Float16* qb = q + (((long)(b * 16384 + p0 + cl)) << 9) + g8;
  const _Float16* kb = k + (((long)(b * 64 + cl)) << 9) + g8;
#pragma unroll
  for (int kk = 0; kk < 16; ++kk) {
    const half8 af = *(const half8*)(qb + kk * 32);
#pragma unroll
    for (int f = 0; f < 4; ++f)
      if (f < nf)
        sc[f] = __builtin_amdgcn_mfma_f32_16x16x32_f16(
            af, *(const half8*)(kb + f * (16 * 512) + kk * 32), sc[f], 0, 0, 0);
  }

  const float SCALE = 0.044194173824159216f;   // 1/sqrt(512)
  float ex[4][4], mj[4], sj[4];
#pragma unroll
  for (int j = 0; j < 4; ++j) {
    float mx = -1e30f;
#pragma unroll
    for (int f = 0; f < 4; ++f) {
      float v = sc[f][j] * SCALE;
      if (f * 16 + cl >= lim) v = -1e30f;
      ex[f][j] = v;
      mx = fmaxf(mx, v);
    }
    mj[j] = mx;
  }
#pragma unroll
  for (int o = 1; o < 16; o <<= 1)
#pragma unroll
    for (int j = 0; j < 4; ++j) mj[j] = fmaxf(mj[j], __shfl_xor(mj[j], o));
#pragma unroll
  for (int j = 0; j < 4; ++j) {
    float s = 0.f;
#pragma unroll
    for (int f = 0; f < 4; ++f) {
      const float e = __expf(ex[f][j] - mj[j]);
      ex[f][j] = e;
      s += e;
    }
    sj[j] = s;
  }
#pragma unroll
  for (int o = 1; o < 16; o <<= 1)
#pragma unroll
    for (int j = 0; j < 4; ++j) sj[j] += __shfl_xor(sj[j], o);
#pragma unroll
  for (int j = 0; j < 4; ++j) {
    const float inv = 1.f / sj[j];
#pragma unroll
    for (int f = 0; f < 4; ++f)
      wlds[w][r4 + j][f * 16 + cl] = (_Float16)(ex[f][j] * inv);
  }

  const half8 wa0 = *(const half8*)&wlds[w][cl][g8];
  const half8 wa1 = *(const half8*)&wlds[w][cl][32 + g8];
#pragma unroll
  for (int hf = 0; hf < 2; ++hf) {
    f32x4 oc[16] = {};
#pragma unroll
    for (int cf = 0; cf < 16; ++cf) {
      const _Float16* vb = vT + (((long)(b * 512 + hf * 256 + cf * 16 + cl)) << 6) + g8;
      oc[cf] = __builtin_amdgcn_mfma_f32_16x16x32_f16(wa0, *(const half8*)vb, oc[cf], 0, 0, 0);
      if (ks == 2)
        oc[cf] = __builtin_amdgcn_mfma_f32_16x16x32_f16(wa1, *(const half8*)(vb + 32), oc[cf], 0, 0, 0);
    }
#pragma unroll
    for (int cf = 0; cf < 16; ++cf)
#pragma unroll
      for (int j = 0; j < 4; ++j)
        O[(((long)(b * 16384 + p0 + r4 + j)) << 9) + hf * 256 + cf * 16 + cl] =
            (_Float16)oc[cf][j];
  }
}

// ---------------------------------------------------------------------------
// launcher
// ---------------------------------------------------------------------------
extern "C" void kernel_launch(void* const* d_in, const int* in_sizes, int n_in,
                              void* d_out, int out_size, void* d_ws, size_t ws_size,
                              hipStream_t stream)
{
  (void)in_sizes; (void)n_in; (void)out_size; (void)ws_size;
  const float* x     = (const float*)d_in[0];
  const float* ctx   = (const float*)d_in[1];
  const float* gamma = (const float*)d_in[2];
  const float* beta  = (const float*)d_in[3];
  const float* wq    = (const float*)d_in[4];
  const float* bq    = (const float*)d_in[5];
  const float* wkv   = (const float*)d_in[6];
  const float* bkv   = (const float*)d_in[7];
  const float* wo    = (const float*)d_in[8];
  const float* bo    = (const float*)d_in[9];
  float* out = (float*)d_out;

  char* ws = (char*)d_ws;
  size_t off = 0;
  auto alloc = [&](size_t bytes) -> void* {
    void* p = ws + off;
    off += (bytes + 255) & ~(size_t)255;
    return p;
  };
  const long HPC = 8388608;                        // 16384*512 per batch
  _Float16* hF   = (_Float16*)alloc(2 * HPC * 2);  // h [b][p][c] f16 (reused for O)
  _Float16* qF   = (_Float16*)alloc(2 * HPC * 2);  // q [b][p][c] f16
  _Float16* wqF  = (_Float16*)alloc(512 * 512 * 2);
  _Float16* woF  = (_Float16*)alloc(512 * 512 * 2);
  _Float16* kF   = (_Float16*)alloc(2 * 64 * 512 * 2);   // k [b][s][c]
  _Float16* vTF  = (_Float16*)alloc(2 * 512 * 64 * 2);   // vT [b][c][s]
  _Float16* oF   = hF;                             // h dead after q-GEMM

  gn_fused<<<dim3(16, 32, 2), 256, 0, stream>>>(x, gamma, beta, hF);
  to_f16<<<dim3(256), 256, 0, stream>>>(wq, wqF, 65536);
  to_f16<<<dim3(256), 256, 0, stream>>>(wo, woF, 65536);
  kv_gemm<<<dim3(64, 2), 256, 0, stream>>>(ctx, wkv, bkv, kF, vTF);

  // q[b][p][o] = h[b][p][:].wq[o][:] + bq[o]  (f16 out; swz mode 2)
  gemm_f16<1, 0, 1, 2><<<dim3(512, 1, 2), 256, 0, stream>>>(
      hF, wqF, qF, bq, nullptr, 512, 512, 512, 512, HPC, 0, HPC, 0);

  attn2<<<dim3(16, 16, 2), 256, 0, stream>>>(qF, kF, vTF, oF);

  // out[b][o][p] = x[b][o][p] + O[b][p][:].wo[o][:] + bo[o]  (f32 out; swz mode 1)
  gemm_f16<0, 1, 0, 1><<<dim3(512, 1, 2), 256, 0, stream>>>(
      woF, oF, out, bo, x, 512, 512, 512, 16384, 0, HPC, HPC, HPC);
}